// Round 9
// baseline (301.110 us; speedup 1.0000x reference)
//
#include <hip/hip_runtime.h>
#include <hip/hip_bf16.h>

#define CIN 32
#define COUT 64
#define SEGS 8
#define SCHUNK 1024

typedef __attribute__((ext_vector_type(8))) short bf16x8;
typedef __attribute__((ext_vector_type(4))) float f32x4;

__device__ inline short bf16r(float x) {
    unsigned u = __float_as_uint(x);
    return (short)((u + 0x7FFFu + ((u >> 16) & 1u)) >> 16);
}

__device__ inline unsigned pk2(float lo, float hi) {
    __hip_bfloat162 t = __float22bfloat162_rn(make_float2(lo, hi));
    return *(unsigned*)&t;
}

// ---------------------------------------------------------------------------
// Fused prep: [0,32) pack weights | [32,32+nbm) gather out_bxyz |
// rest: featb = 64B line-aligned bf16 rows (exactly CIN=32 bf16).
__global__ void prep_kernel(const float* __restrict__ W1,
                            const float* __restrict__ W2,
                            short* __restrict__ wpack,
                            const float4* __restrict__ bxyz4,
                            const int* __restrict__ sidx,
                            float4* __restrict__ out_bxyz,
                            const float* __restrict__ feat,
                            uint4* __restrict__ featb,
                            int M, int N, int nbm) {
    int b = blockIdx.x, tid = threadIdx.x;
    if (b < 32) {
        int t = b * 256 + tid;                 // 8192 exactly
        int e = t & 7, l = (t >> 3) & 63, f = t >> 9;
        int g = l >> 4, n16 = l & 15;
        int kc = (f & 7) >> 2, nt = f & 3;
        int k = kc * 32 + g * 8 + e;
        int n = nt * 16 + n16;
        float v;
        if (f < 8) v = (k < CIN + 3) ? W1[k * COUT + n] : 0.f;
        else       v = W2[k * COUT + n];
        wpack[t] = bf16r(v);
    } else if (b < 32 + nbm) {
        int i = (b - 32) * 256 + tid;
        if (i < M) out_bxyz[i] = bxyz4[sidx[i]];
    } else {
        int p = (b - 32 - nbm) * 256 + tid;
        if (p < N) {
            const float4* s = (const float4*)(feat + (size_t)p * CIN);
            float4 f0 = s[0], f1 = s[1], f2 = s[2], f3 = s[3];
            float4 f4 = s[4], f5 = s[5], f6 = s[6], f7 = s[7];
            uint4* d = featb + (size_t)p * 4;
            d[0] = make_uint4(pk2(f0.x, f0.y), pk2(f0.z, f0.w), pk2(f1.x, f1.y), pk2(f1.z, f1.w));
            d[1] = make_uint4(pk2(f2.x, f2.y), pk2(f2.z, f2.w), pk2(f3.x, f3.y), pk2(f3.z, f3.w));
            d[2] = make_uint4(pk2(f4.x, f4.y), pk2(f4.z, f4.w), pk2(f5.x, f5.y), pk2(f5.z, f5.w));
            d[3] = make_uint4(pk2(f6.x, f6.y), pk2(f6.z, f6.w), pk2(f7.x, f7.y), pk2(f7.z, f7.w));
        }
    }
}

// ---------------------------------------------------------------------------
// Ticketing: one returning-atomic pass; loc[e] = within-segment position.
__global__ void histloc_kernel(const int4* __restrict__ e_new4,
                               int* __restrict__ counts,
                               int4* __restrict__ loc4, int E8) {
    int i = blockIdx.x * blockDim.x + threadIdx.x;
    if (i >= E8) return;
    int4 a = e_new4[i * 2];
    int4 b = e_new4[i * 2 + 1];
    int4 la, lb;
    la.x = atomicAdd(&counts[a.x], 1);
    la.y = atomicAdd(&counts[a.y], 1);
    la.z = atomicAdd(&counts[a.z], 1);
    la.w = atomicAdd(&counts[a.w], 1);
    lb.x = atomicAdd(&counts[b.x], 1);
    lb.y = atomicAdd(&counts[b.y], 1);
    lb.z = atomicAdd(&counts[b.z], 1);
    lb.w = atomicAdd(&counts[b.w], 1);
    loc4[i * 2]     = la;
    loc4[i * 2 + 1] = lb;
}

// ---------------------------------------------------------------------------
// Scan of per-seg TILE counts ((cnt+15)/16) -> padded tile starts.
// Also zeroes out_feat rows of empty segments (rare branch).
__global__ void scanA_kernel(const int* __restrict__ counts,
                             int* __restrict__ row1,
                             int* __restrict__ sums,
                             float4* __restrict__ out_feat4, int M) {
    __shared__ int lds[256];
    int t = threadIdx.x, blk = blockIdx.x;
    int base = blk * SCHUNK + t * 4;
    int c0 = (base + 0 < M) ? counts[base + 0] : 1;
    int c1 = (base + 1 < M) ? counts[base + 1] : 1;
    int c2 = (base + 2 < M) ? counts[base + 2] : 1;
    int c3 = (base + 3 < M) ? counts[base + 3] : 1;
    float4 z = make_float4(0.f, 0.f, 0.f, 0.f);
    if (c0 == 0) { float4* o = out_feat4 + (size_t)(base + 0) * 16;
#pragma unroll
        for (int i = 0; i < 16; ++i) o[i] = z; }
    if (c1 == 0) { float4* o = out_feat4 + (size_t)(base + 1) * 16;
#pragma unroll
        for (int i = 0; i < 16; ++i) o[i] = z; }
    if (c2 == 0) { float4* o = out_feat4 + (size_t)(base + 2) * 16;
#pragma unroll
        for (int i = 0; i < 16; ++i) o[i] = z; }
    if (c3 == 0) { float4* o = out_feat4 + (size_t)(base + 3) * 16;
#pragma unroll
        for (int i = 0; i < 16; ++i) o[i] = z; }
    int v0 = (base + 0 < M) ? (c0 + 15) >> 4 : 0;
    int v1 = (base + 1 < M) ? (c1 + 15) >> 4 : 0;
    int v2 = (base + 2 < M) ? (c2 + 15) >> 4 : 0;
    int v3 = (base + 3 < M) ? (c3 + 15) >> 4 : 0;
    int s = v0 + v1 + v2 + v3;
    int val = s;
    lds[t] = val; __syncthreads();
    for (int off = 1; off < 256; off <<= 1) {
        int x = (t >= off) ? lds[t - off] : 0;
        __syncthreads();
        val += x; lds[t] = val;
        __syncthreads();
    }
    int ex = val - s;
    if (base + 0 < M) row1[base + 0] = ex + v0;
    if (base + 1 < M) row1[base + 1] = ex + v0 + v1;
    if (base + 2 < M) row1[base + 2] = ex + v0 + v1 + v2;
    if (base + 3 < M) row1[base + 3] = ex + s;
    if (t == 255) sums[blk] = val;
}

// scanC with scanB folded in (nchunks<=256).
__global__ void scanC_kernel(int* __restrict__ row1,
                             const int* __restrict__ sums,
                             int* __restrict__ tstart, int M) {
    __shared__ int lds[256];
    int blk = blockIdx.x, t = threadIdx.x;
    lds[t] = (t < blk) ? sums[t] : 0;
    __syncthreads();
    for (int off = 128; off > 0; off >>= 1) {
        if (t < off) lds[t] += lds[t + off];
        __syncthreads();
    }
    int off0 = lds[0];
    if (blk == 0 && t == 0) tstart[0] = 0;
    int base = blk * SCHUNK + t * 4;
#pragma unroll
    for (int i = 0; i < 4; ++i)
        if (base + i < M) row1[base + i] += off0;
}

// ---------------------------------------------------------------------------
// Placement into PADDED csr (every tile = 16 edges of one segment).
// The ticket-0 edge also writes the pad slots (dups of itself) + tile_meta.
__global__ void place_kernel(const int4* __restrict__ e_new4,
                             const int4* __restrict__ e_point4,
                             const int4* __restrict__ loc4,
                             const int* __restrict__ tstart,
                             const int* __restrict__ counts,
                             int* __restrict__ csr_ep,
                             int* __restrict__ tile_meta, int E8) {
    int i = blockIdx.x * blockDim.x + threadIdx.x;
    if (i >= E8) return;
    int4 n0 = e_new4[i * 2],   n1 = e_new4[i * 2 + 1];
    int4 p0 = e_point4[i * 2], p1 = e_point4[i * 2 + 1];
    int4 l0 = loc4[i * 2],     l1 = loc4[i * 2 + 1];
    int segs[8] = {n0.x, n0.y, n0.z, n0.w, n1.x, n1.y, n1.z, n1.w};
    int eps[8]  = {p0.x, p0.y, p0.z, p0.w, p1.x, p1.y, p1.z, p1.w};
    int locs[8] = {l0.x, l0.y, l0.z, l0.w, l1.x, l1.y, l1.z, l1.w};
#pragma unroll
    for (int k = 0; k < 8; ++k) {
        int seg = segs[k], ep = eps[k], lc = locs[k];
        int tst = tstart[seg];
        int prow = tst * 16;
        csr_ep[prow + lc] = ep;
        if (lc == 0) {
            int cnt = counts[seg];
            int ntl = (cnt + 15) >> 4;
            for (int j = cnt; j < ntl * 16; ++j) csr_ep[prow + j] = ep;
            for (int j = 0; j < ntl; ++j)
                tile_meta[tst + j] = (seg << 1) | (j == ntl - 1);
        }
    }
}

// ---------------------------------------------------------------------------
// Aggregation: wave handles SEGS segments as a FLAT padded-tile range
// [tstart[s0], tstart[s1]) -- trivial t++ cursor, per-tile meta gives
// (seg, last). Swizzle X(row)=(row&7)<<4: writes 2 lanes/bank (free),
// b128 reads give 8 distinct granules per in-order 8-lane group (the R4
// empirically-0-conflict pattern).
__global__ __launch_bounds__(256)
void agg_kernel(const bf16x8* __restrict__ featb,   // [N][4] chunks
                const float4* __restrict__ bxyz4,
                const int* __restrict__ csr_ep,     // padded
                const int* __restrict__ tstart,     // [M+1]
                const int* __restrict__ tile_meta,  // (seg<<1)|last
                const bf16x8* __restrict__ wpack,
                const float* __restrict__ b1,
                const float* __restrict__ b2,
                const float* __restrict__ W1,
                const float4* __restrict__ new_bxyz4,
                float* __restrict__ out_feat, int M) {
    __shared__ char h1buf[4][4096];
    const int lane = threadIdx.x & 63;
    const int w    = threadIdx.x >> 6;
    const int m    = lane & 15;
    const int g    = lane >> 4;

    int s0 = (blockIdx.x * 4 + w) * SEGS;
    if (s0 >= M) return;
    int s1 = min(s0 + SEGS, M);
    int tb = tstart[s0], te = tstart[s1];
    int n = te - tb;
    if (n <= 0) return;

    bf16x8 w1b[8], w2b[8];
#pragma unroll
    for (int f = 0; f < 8; ++f) w1b[f] = wpack[f * 64 + lane];
#pragma unroll
    for (int f = 0; f < 8; ++f) w2b[f] = wpack[(8 + f) * 64 + lane];

    float b1v[4], b2v[4], w1r0[4], w1r1[4], w1r2[4];
#pragma unroll
    for (int nt = 0; nt < 4; ++nt) {
        int col = nt * 16 + m;
        b1v[nt]  = b1[col];
        b2v[nt]  = b2[col];
        w1r0[nt] = W1[32 * COUT + col];
        w1r1[nt] = W1[33 * COUT + col];
        w1r2[nt] = W1[34 * COUT + col];
    }

    char* h1p = h1buf[w];
    int wA[8];
#pragma unroll
    for (int q = 0; q < 4; ++q) {
        int row = g * 4 + q;
        int kk = (row & 7) << 4;
        wA[q * 2 + 0] = (row * 256 + m * 4) ^ kk;
        wA[q * 2 + 1] = (row * 256 + (m + 16) * 4) ^ kk;
    }
    const int frm = (m & 7) << 4;
    const int rb0 = (m * 256 + g * 32) ^ frm;
    const int rb1 = (m * 256 + g * 32 + 16) ^ frm;

    f32x4 accv = {0.f, 0.f, 0.f, 0.f};

    int meta0, meta1, meta2, ep0, ep1, ep2;
    bf16x8 a10, a11, a12;
    float4 pb0, pb1, pb2, nb0, nb1, nb2;

#define LOADSLOT(S, TI)                                                       \
    do {                                                                      \
        int ti_ = (TI);                                                       \
        meta##S = tile_meta[ti_];                                             \
        ep##S   = csr_ep[ti_ * 16 + m];                                       \
        nb##S   = new_bxyz4[meta##S >> 1];                                    \
        a1##S   = featb[(size_t)(unsigned)ep##S * 4 + g];                     \
        pb##S   = make_float4(0.f, 0.f, 0.f, 0.f);                            \
        if (g == 0) pb##S = bxyz4[ep##S];                                     \
    } while (0)

#define COMPUTE(S)                                                            \
    do {                                                                      \
        bool lastT = meta##S & 1;                                             \
        int  segv  = meta##S >> 1;                                            \
        short u0 = bf16r(pb##S.y), u1 = bf16r(pb##S.z), u2 = bf16r(pb##S.w);  \
        bf16x8 a2 = {0, 0, 0, 0, 0, 0, 0, 0};                                 \
        if (g == 0) { a2[0] = u0; a2[1] = u1; a2[2] = u2; }                   \
        f32x4 acc_[4];                                                        \
        _Pragma("unroll")                                                     \
        for (int nt = 0; nt < 4; ++nt) {                                      \
            float be = b1v[nt] - nb##S.y * w1r0[nt] - nb##S.z * w1r1[nt]      \
                                - nb##S.w * w1r2[nt];                         \
            f32x4 cc = {be, be, be, be};                                      \
            cc = __builtin_amdgcn_mfma_f32_16x16x32_bf16(a1##S, w1b[nt], cc, 0, 0, 0); \
            cc = __builtin_amdgcn_mfma_f32_16x16x32_bf16(a2, w1b[4 + nt], cc, 0, 0, 0); \
            acc_[nt] = cc;                                                    \
        }                                                                     \
        _Pragma("unroll")                                                     \
        for (int nt = 0; nt < 4; ++nt)                                        \
            _Pragma("unroll")                                                 \
            for (int q = 0; q < 4; ++q)                                       \
                *(float*)(h1p + wA[q * 2 + (nt & 1)] + (nt >> 1) * 128) =     \
                    fmaxf(acc_[nt][q], 0.f);                                  \
        float4 q0 = *(const float4*)(h1p + rb0);                              \
        float4 q1 = *(const float4*)(h1p + rb1);                              \
        float4 q2 = *(const float4*)(h1p + rb0 + 128);                        \
        float4 q3 = *(const float4*)(h1p + rb1 + 128);                        \
        union { bf16x8 v; unsigned u[4]; } A30, A31;                          \
        A30.u[0] = pk2(q0.x, q0.y); A30.u[1] = pk2(q0.z, q0.w);               \
        A30.u[2] = pk2(q1.x, q1.y); A30.u[3] = pk2(q1.z, q1.w);               \
        A31.u[0] = pk2(q2.x, q2.y); A31.u[1] = pk2(q2.z, q2.w);               \
        A31.u[2] = pk2(q3.x, q3.y); A31.u[3] = pk2(q3.z, q3.w);               \
        _Pragma("unroll")                                                     \
        for (int nt = 0; nt < 4; ++nt) {                                      \
            f32x4 cc = {b2v[nt], b2v[nt], b2v[nt], b2v[nt]};                  \
            cc = __builtin_amdgcn_mfma_f32_16x16x32_bf16(A30.v, w2b[nt], cc, 0, 0, 0); \
            cc = __builtin_amdgcn_mfma_f32_16x16x32_bf16(A31.v, w2b[4 + nt], cc, 0, 0, 0); \
            float t2 = fmaxf(fmaxf(cc[0], cc[1]), fmaxf(cc[2], cc[3]));       \
            accv[nt] = fmaxf(accv[nt], t2);                                   \
        }                                                                     \
        if (lastT) {                                                          \
            _Pragma("unroll")                                                 \
            for (int nt = 0; nt < 4; ++nt) {                                  \
                float v = accv[nt];                                           \
                v = fmaxf(v, __shfl_xor(v, 16));                              \
                v = fmaxf(v, __shfl_xor(v, 32));                              \
                accv[nt] = v;                                                 \
            }                                                                 \
            float outv = (g == 0) ? accv[0] : (g == 1) ? accv[1]              \
                       : (g == 2) ? accv[2] : accv[3];                        \
            out_feat[(size_t)segv * COUT + lane] = outv;                      \
            accv[0] = accv[1] = accv[2] = accv[3] = 0.f;                      \
        }                                                                     \
    } while (0)

    LOADSLOT(0, tb);
    LOADSLOT(1, tb + min(1, n - 1));
    LOADSLOT(2, tb + min(2, n - 1));

    int i = 0;
    for (;;) {
        if (i >= n) break; COMPUTE(0); LOADSLOT(0, tb + min(i + 3, n - 1)); ++i;
        if (i >= n) break; COMPUTE(1); LOADSLOT(1, tb + min(i + 3, n - 1)); ++i;
        if (i >= n) break; COMPUTE(2); LOADSLOT(2, tb + min(i + 3, n - 1)); ++i;
    }
#undef LOADSLOT
#undef COMPUTE
}

// ---------------------------------------------------------------------------
extern "C" void kernel_launch(void* const* d_in, const int* in_sizes, int n_in,
                              void* d_out, int out_size, void* d_ws, size_t ws_size,
                              hipStream_t stream) {
    const float* bxyz   = (const float*)d_in[0];
    const float* feat   = (const float*)d_in[1];
    const int*   sidx   = (const int*)d_in[2];
    const int*   e_pt   = (const int*)d_in[3];
    const int*   e_new  = (const int*)d_in[4];
    const float* W1     = (const float*)d_in[5];
    const float* b1     = (const float*)d_in[6];
    const float* W2     = (const float*)d_in[7];
    const float* b2     = (const float*)d_in[8];

    const int N = in_sizes[0] / 4;
    const int M = in_sizes[2];
    const int E = in_sizes[3];

    float* out_bxyz = (float*)d_out;                 // [M][4]
    float* out_feat = out_bxyz + (size_t)M * 4;      // [M][64]

    // ws layout (16B aligned regions)
    char*  ws        = (char*)d_ws;
    short* wpack     = (short*)ws;                                    // 16 KiB
    size_t off_cnt   = 16384;
    int*   counts    = (int*)(ws + off_cnt);                          // M
    size_t off_ts    = off_cnt + (((size_t)M * 4 + 15) & ~(size_t)15);
    int*   tstart    = (int*)(ws + off_ts);                           // M+4
    size_t off_sums  = off_ts + ((((size_t)M + 4) * 4 + 15) & ~(size_t)15);
    int*   sums      = (int*)(ws + off_sums);                         // 256
    size_t off_loc   = off_sums + 1024;
    int*   loc       = (int*)(ws + off_loc);                          // E
    size_t off_csr   = off_loc + (size_t)E * 4;
    size_t csr_cap   = (size_t)E + 15 * (size_t)M + 64;               // padded
    int*   csr_ep    = (int*)(ws + off_csr);
    size_t off_meta  = off_csr + csr_cap * 4;
    int*   tile_meta = (int*)(ws + off_meta);                         // csr_cap/16
    size_t off_fb    = (off_meta + (csr_cap / 16 + 64) * 4 + 63) & ~(size_t)63;
    uint4* featb     = (uint4*)(ws + off_fb);                         // N*64B
    int*   row1      = tstart + 1;

    int nbm     = (M + 255) / 256;
    int nbp     = (N + 255) / 256;
    int nchunks = (M + SCHUNK - 1) / SCHUNK;   // 123 for M=125000 (<=256 req.)
    int E8      = E / 8;

    hipMemsetAsync(counts, 0, (size_t)M * 4, stream);

    prep_kernel<<<32 + nbm + nbp, 256, 0, stream>>>(
        W1, W2, wpack, (const float4*)bxyz, sidx, (float4*)out_bxyz,
        feat, featb, M, N, nbm);

    histloc_kernel<<<(E8 + 255) / 256, 256, 0, stream>>>(
        (const int4*)e_new, counts, (int4*)loc, E8);
    scanA_kernel<<<nchunks, 256, 0, stream>>>(
        counts, row1, sums, (float4*)out_feat, M);
    scanC_kernel<<<nchunks, 256, 0, stream>>>(row1, sums, tstart, M);
    place_kernel<<<(E8 + 255) / 256, 256, 0, stream>>>(
        (const int4*)e_new, (const int4*)e_pt, (const int4*)loc,
        tstart, counts, csr_ep, tile_meta, E8);

    int nblocks = (M + 4 * SEGS - 1) / (4 * SEGS);
    agg_kernel<<<nblocks, 256, 0, stream>>>(
        (const bf16x8*)featb, (const float4*)bxyz, csr_ep, tstart, tile_meta,
        (const bf16x8*)wpack, b1, b2, W1, (const float4*)out_bxyz, out_feat, M);
}